// Round 4
// baseline (275.817 us; speedup 1.0000x reference)
//
#include <hip/hip_runtime.h>

// AdaptiveSoftmax on MI355X — round 4.
// R3 post-mortem: k_sumexp 124us, MfmaUtil 18.4% (~440 TF effective — the
// 64x64-tile VGPR-staged rung of the measured ladder), ~50% stall.
// R4: m97-class structure for head/tail0/hgemm: 128x128 tiles, 4x4 acc/wave,
// global_load_lds(16B) staging (no VGPR round-trip), 32KB single-buffer LDS,
// XOR swizzle applied on the GLOBAL address side (coalescing unchanged,
// fragment reads keep R3's zero-conflict pattern). Tail1: 128 rows/wave
// streaming (half the B traffic). Phase interleave period 33 (8H/9T0/16T1).

typedef __attribute__((ext_vector_type(8))) short short8;
typedef __attribute__((ext_vector_type(4))) float f32x4;

#define LOG2E 1.4426950408889634f
#define LN2   0.6931471805599453f

__device__ __forceinline__ float b2f(unsigned short u){
    return __uint_as_float(((unsigned int)u) << 16);
}
__device__ __forceinline__ unsigned short f2b(float f){
    unsigned int x = __float_as_uint(f);
    x += 0x7fffu + ((x >> 16) & 1u);
    return (unsigned short)(x >> 16);
}
__device__ __forceinline__ float dotu(unsigned int xu, unsigned int wu){
    float a = __uint_as_float(xu << 16) * __uint_as_float(wu << 16);
    float b = __uint_as_float(xu & 0xffff0000u) * __uint_as_float(wu & 0xffff0000u);
    return a + b;
}
__device__ __forceinline__ float fexp2(float x){
#if __has_builtin(__builtin_amdgcn_exp2f)
    return __builtin_amdgcn_exp2f(x);
#else
    float r; asm("v_exp_f32 %0, %1" : "=v"(r) : "v"(x)); return r;
#endif
}
// async global->LDS, 16B per lane; lptr wave-uniform base, lane i lands at +16*i
__device__ __forceinline__ void gload16(const unsigned short* g, unsigned short* l){
    __builtin_amdgcn_global_load_lds(
        (const __attribute__((address_space(1))) unsigned int*)g,
        (__attribute__((address_space(3))) unsigned int*)l, 16, 0, 0);
}

// ---------------- prep: converts + LDS-tiled transposes + zero sums ---------
__global__ __launch_bounds__(256) void k_prep(
    const float* __restrict__ X, const float* __restrict__ headW,
    const float* __restrict__ emb0, const float* __restrict__ emb1,
    const float* __restrict__ lin0, const float* __restrict__ lin1,
    unsigned short* __restrict__ Xb, unsigned short* __restrict__ hWb,
    unsigned short* __restrict__ e0b, unsigned short* __restrict__ e1b,
    unsigned short* __restrict__ l0T, unsigned short* __restrict__ l1T,
    float* __restrict__ sums)
{
    __shared__ unsigned short tileT[64][65];
    const int b = blockIdx.x, t = threadIdx.x;
    if (b < 80){
        const float* src; unsigned short* dst; int C, tx, ty;
        if (b < 64){ src = lin0; dst = l0T; C = 256; tx = b & 3; ty = b >> 2; }
        else       { src = lin1; dst = l1T; C = 64;  tx = 0;     ty = b - 64; }
        #pragma unroll
        for (int e = 0; e < 16; ++e){
            int idx = t + e*256, r = idx >> 6, c = idx & 63;
            tileT[c][r] = f2b(src[(ty*64 + r)*C + tx*64 + c]);
        }
        __syncthreads();
        #pragma unroll
        for (int e = 0; e < 16; ++e){
            int idx = t + e*256, cc = idx >> 6, rr = idx & 63;
            dst[(tx*64 + cc)*1024 + ty*64 + rr] = tileT[cc][rr];
        }
        return;
    }
    const int NX = 1048576, NH = 512512, NE0 = 512000, NE1 = 644112;
    const int NV = NX + NH + NE0 + NE1;
    const int NS = 12288;
    const int total = NV + NS;
    int stride = (gridDim.x - 80) * blockDim.x;
    for (int i = (b - 80)*blockDim.x + t; i < total; i += stride){
        if (i < NV){
            const float* src; unsigned short* dst; int off; float sc;
            if (i < NX)            { src = X;     dst = Xb;  off = i;           sc = 1.0f;  }
            else if (i < NX+NH)    { src = headW; dst = hWb; off = i-NX;        sc = LOG2E; }
            else if (i < NX+NH+NE0){ src = emb0;  dst = e0b; off = i-NX-NH;     sc = LOG2E; }
            else                   { src = emb1;  dst = e1b; off = i-NX-NH-NE0; sc = LOG2E; }
            float4 v = ((const float4*)src)[off];
            ushort4 o;
            o.x = f2b(v.x*sc); o.y = f2b(v.y*sc);
            o.z = f2b(v.z*sc); o.w = f2b(v.w*sc);
            ((ushort4*)dst)[off] = o;
        } else {
            sums[i - NV] = 0.f;
        }
    }
}

// ---------- m97-style 128x128 GEMM core pieces (shared by hgemm/sumexp) -----
// LDS layout: [128 rows][64 k] bf16, swizzled: row r, k-group g (8 elems)
// stored at slot (g ^ (r&7)). Staging fetches the permuted group per lane so
// global_load_lds's lane-contiguous write realizes this layout.

// ------------- h-GEMM: h = X @ linT^T, lin concat [320][1024] ---------------
__global__ __launch_bounds__(256) void k_hgemm(
    const unsigned short* __restrict__ A,    // Xb [4096][1024]
    const unsigned short* __restrict__ B,    // l0T|l1T [320][1024]
    unsigned short* __restrict__ C0,         // h0b [4096][256]
    unsigned short* __restrict__ C1)         // h1b [4096][64]
{
    constexpr int K = 1024;
    __shared__ __align__(16) unsigned short As[128*64];
    __shared__ __align__(16) unsigned short Bs[128*64];
    const int rowb = blockIdx.x / 3, cb = blockIdx.x % 3;
    const int tid = threadIdx.x, lane = tid & 63, w = tid >> 6;
    const int waveR = w >> 1, waveC = w & 1;
    const int quad = lane >> 4, l16 = lane & 15;
    const int row0 = rowb * 128;
    const int srow = w*32 + (lane >> 3);
    const int gk   = ((lane & 7) ^ (srow & 7)) << 3;
    unsigned short* ldsA = As + w*4*512;
    unsigned short* ldsB = Bs + w*4*512;
    const int sA = (waveR*64 + l16)*64 + ((quad ^ (l16 & 7)) << 3);
    const int sB = (waveC*64 + l16)*64 + ((quad ^ (l16 & 7)) << 3);

    f32x4 acc[4][4];
    #pragma unroll
    for (int i = 0; i < 4; ++i)
    #pragma unroll
    for (int j = 0; j < 4; ++j) acc[i][j] = (f32x4){0.f,0.f,0.f,0.f};

    for (int kc = 0; kc < K/64; ++kc){
        __syncthreads();
        const unsigned short* gA = A + (size_t)(row0 + srow)*K + kc*64 + gk;
        #pragma unroll
        for (int c = 0; c < 4; ++c)
            gload16(gA + c*8*K, ldsA + c*512);
        #pragma unroll
        for (int c = 0; c < 4; ++c){
            int br = min(cb*128 + srow + c*8, 319);
            gload16(B + (size_t)br*K + kc*64 + gk, ldsB + c*512);
        }
        __syncthreads();
        #pragma unroll
        for (int ks = 0; ks < 2; ++ks){
            const int xo = ks << 5;
            short8 a0 = *(const short8*)&As[(sA ^ xo)         ];
            short8 a1 = *(const short8*)&As[(sA ^ xo) + 1024  ];
            short8 a2 = *(const short8*)&As[(sA ^ xo) + 2048  ];
            short8 a3 = *(const short8*)&As[(sA ^ xo) + 3072  ];
            short8 b0 = *(const short8*)&Bs[(sB ^ xo)         ];
            short8 b1 = *(const short8*)&Bs[(sB ^ xo) + 1024  ];
            short8 b2 = *(const short8*)&Bs[(sB ^ xo) + 2048  ];
            short8 b3 = *(const short8*)&Bs[(sB ^ xo) + 3072  ];
            #pragma unroll
            for (int i = 0; i < 4; ++i){
                short8 av = (i==0)?a0:(i==1)?a1:(i==2)?a2:a3;
                acc[i][0] = __builtin_amdgcn_mfma_f32_16x16x32_bf16(av, b0, acc[i][0], 0,0,0);
                acc[i][1] = __builtin_amdgcn_mfma_f32_16x16x32_bf16(av, b1, acc[i][1], 0,0,0);
                acc[i][2] = __builtin_amdgcn_mfma_f32_16x16x32_bf16(av, b2, acc[i][2], 0,0,0);
                acc[i][3] = __builtin_amdgcn_mfma_f32_16x16x32_bf16(av, b3, acc[i][3], 0,0,0);
            }
        }
    }
    #pragma unroll
    for (int i = 0; i < 4; ++i)
    #pragma unroll
    for (int j = 0; j < 4; ++j)
    #pragma unroll
    for (int r = 0; r < 4; ++r){
        int row = row0 + waveR*64 + i*16 + quad*4 + r;
        int col = cb*128 + waveC*64 + j*16 + l16;
        if (col < 256) C0[row*256 + col] = f2b(acc[i][j][r]);
        else if (col < 320) C1[row*64 + (col - 256)] = f2b(acc[i][j][r]);
    }
}

// ------------- sumexp over a 128-row band, m97 structure --------------------
template<int K>
__device__ __forceinline__ void sumexp128(
    const unsigned short* __restrict__ A,   // [4096][K]
    const unsigned short* __restrict__ B,   // [M][K] (pre-scaled by log2e)
    float* __restrict__ s_out, int M,
    int rowb, int cb0, int cb1,
    unsigned short* __restrict__ As, unsigned short* __restrict__ Bs)
{
    constexpr int KCH = K / 64;
    const int tid = threadIdx.x, lane = tid & 63, w = tid >> 6;
    const int waveR = w >> 1, waveC = w & 1;
    const int quad = lane >> 4, l16 = lane & 15;
    const int row0 = rowb * 128;
    const int srow = w*32 + (lane >> 3);
    const int gk   = ((lane & 7) ^ (srow & 7)) << 3;
    unsigned short* ldsA = As + w*4*512;
    unsigned short* ldsB = Bs + w*4*512;
    const int sA = (waveR*64 + l16)*64 + ((quad ^ (l16 & 7)) << 3);
    const int sB = (waveC*64 + l16)*64 + ((quad ^ (l16 & 7)) << 3);

    float s_loc[16];
    #pragma unroll
    for (int i = 0; i < 16; ++i) s_loc[i] = 0.f;

    for (int cb = cb0; cb < cb1; ++cb){
        f32x4 acc[4][4];
        #pragma unroll
        for (int i = 0; i < 4; ++i)
        #pragma unroll
        for (int j = 0; j < 4; ++j) acc[i][j] = (f32x4){0.f,0.f,0.f,0.f};

        for (int kc = 0; kc < KCH; ++kc){
            __syncthreads();
            const unsigned short* gA = A + (size_t)(row0 + srow)*K + kc*64 + gk;
            #pragma unroll
            for (int c = 0; c < 4; ++c)
                gload16(gA + c*8*K, ldsA + c*512);
            #pragma unroll
            for (int c = 0; c < 4; ++c){
                int br = min(cb*128 + srow + c*8, M-1);
                gload16(B + (size_t)br*K + kc*64 + gk, ldsB + c*512);
            }
            __syncthreads();
            #pragma unroll
            for (int ks = 0; ks < 2; ++ks){
                const int xo = ks << 5;
                short8 a0 = *(const short8*)&As[(sA ^ xo)        ];
                short8 a1 = *(const short8*)&As[(sA ^ xo) + 1024 ];
                short8 a2 = *(const short8*)&As[(sA ^ xo) + 2048 ];
                short8 a3 = *(const short8*)&As[(sA ^ xo) + 3072 ];
                short8 b0 = *(const short8*)&Bs[(sB ^ xo)        ];
                short8 b1 = *(const short8*)&Bs[(sB ^ xo) + 1024 ];
                short8 b2 = *(const short8*)&Bs[(sB ^ xo) + 2048 ];
                short8 b3 = *(const short8*)&Bs[(sB ^ xo) + 3072 ];
                #pragma unroll
                for (int i = 0; i < 4; ++i){
                    short8 av = (i==0)?a0:(i==1)?a1:(i==2)?a2:a3;
                    acc[i][0] = __builtin_amdgcn_mfma_f32_16x16x32_bf16(av, b0, acc[i][0], 0,0,0);
                    acc[i][1] = __builtin_amdgcn_mfma_f32_16x16x32_bf16(av, b1, acc[i][1], 0,0,0);
                    acc[i][2] = __builtin_amdgcn_mfma_f32_16x16x32_bf16(av, b2, acc[i][2], 0,0,0);
                    acc[i][3] = __builtin_amdgcn_mfma_f32_16x16x32_bf16(av, b3, acc[i][3], 0,0,0);
                }
            }
        }
        // epilogue: s_loc += 2^logit over the 128x128 chunk
        bool full = ((cb + 1)*128 <= M);
        #pragma unroll
        for (int j = 0; j < 4; ++j){
            if (!full){
                int col = cb*128 + waveC*64 + j*16 + l16;
                if (col >= M) continue;
            }
            #pragma unroll
            for (int i = 0; i < 4; ++i)
            #pragma unroll
            for (int r = 0; r < 4; ++r)
                s_loc[i*4 + r] += fexp2(acc[i][j][r]);
        }
    }

    #pragma unroll
    for (int k = 0; k < 16; ++k){
        s_loc[k] += __shfl_xor(s_loc[k], 1, 64);
        s_loc[k] += __shfl_xor(s_loc[k], 2, 64);
        s_loc[k] += __shfl_xor(s_loc[k], 4, 64);
        s_loc[k] += __shfl_xor(s_loc[k], 8, 64);
    }
    if (l16 == 0){
        #pragma unroll
        for (int k = 0; k < 16; ++k){
            int row = row0 + waveR*64 + (k >> 2)*16 + quad*4 + (k & 3);
            atomicAdd(&s_out[row], s_loc[k]);
        }
    }
}

// ------------- tail1 (K=64): barrier-free streaming, 128 rows/wave ----------
__device__ __forceinline__ void sumexp_stream128(
    const unsigned short* __restrict__ A,   // h1b [4096][64]
    const unsigned short* __restrict__ B,   // e1b [40257][64] (scaled)
    float* __restrict__ s_out, int wid)     // wid in [0, 2048)
{
    const int M = 40257;
    const int lane = threadIdx.x & 63;
    const int quad = lane >> 4, l16 = lane & 15;
    const int rowg  = wid >> 6;             // 0..31, 128 rows each
    const int split = wid & 63;
    const int g0 = split*39 + min(split, 21);
    const int g1 = g0 + 39 + (split < 21 ? 1 : 0);
    const int row0 = rowg * 128;

    short8 a[8][2];
    #pragma unroll
    for (int i = 0; i < 8; ++i)
    #pragma unroll
    for (int ks = 0; ks < 2; ++ks)
        a[i][ks] = *(const short8*)(A + (row0 + i*16 + l16)*64 + ks*32 + quad*8);

    f32x4 sums[8];
    #pragma unroll
    for (int i = 0; i < 8; ++i) sums[i] = (f32x4){0.f,0.f,0.f,0.f};

    short8 p0a, p1a, p0b, p1b;
    auto loadB = [&](int g, short8& d0, short8& d1){
        int n = g*16 + l16; if (n > M-1) n = M-1;
        const unsigned short* p = B + n*64 + quad*8;
        d0 = *(const short8*)p;
        d1 = *(const short8*)(p + 32);
    };
    auto body = [&](int g, short8 b0, short8 b1){
        f32x4 acc[8];
        #pragma unroll
        for (int i = 0; i < 8; ++i) acc[i] = (f32x4){0.f,0.f,0.f,0.f};
        #pragma unroll
        for (int i = 0; i < 8; ++i)
            acc[i] = __builtin_amdgcn_mfma_f32_16x16x32_bf16(a[i][0], b0, acc[i], 0,0,0);
        #pragma unroll
        for (int i = 0; i < 8; ++i)
            acc[i] = __builtin_amdgcn_mfma_f32_16x16x32_bf16(a[i][1], b1, acc[i], 0,0,0);
        if (g*16 + l16 < M){
            #pragma unroll
            for (int i = 0; i < 8; ++i){
                sums[i][0] += fexp2(acc[i][0]);
                sums[i][1] += fexp2(acc[i][1]);
                sums[i][2] += fexp2(acc[i][2]);
                sums[i][3] += fexp2(acc[i][3]);
            }
        }
    };

    loadB(g0, p0a, p1a);
    loadB(g0 + 1, p0b, p1b);
    for (int g = g0; g < g1; g += 2){
        body(g, p0a, p1a);
        if (g + 2 < g1) loadB(g + 2, p0a, p1a);
        if (g + 1 < g1){
            body(g + 1, p0b, p1b);
            if (g + 3 < g1) loadB(g + 3, p0b, p1b);
        }
    }

    #pragma unroll
    for (int i = 0; i < 8; ++i){
        #pragma unroll
        for (int r = 0; r < 4; ++r){
            float v = sums[i][r];
            v += __shfl_xor(v, 1, 64);
            v += __shfl_xor(v, 2, 64);
            v += __shfl_xor(v, 4, 64);
            v += __shfl_xor(v, 8, 64);
            if (l16 == 0)
                atomicAdd(&s_out[row0 + i*16 + quad*4 + r], v);
        }
    }
}

// ------------- fused sumexp dispatch (period-33 interleave) -----------------
// 1056 blocks = 32 groups x 33: 8 head + 9 tail0 + 16 tail1 per group.
__global__ __launch_bounds__(256) void k_sumexp(
    const unsigned short* __restrict__ Xb,  const unsigned short* __restrict__ hWb,
    const unsigned short* __restrict__ h0b, const unsigned short* __restrict__ e0b,
    const unsigned short* __restrict__ h1b, const unsigned short* __restrict__ e1b,
    float* __restrict__ sH, float* __restrict__ s0, float* __restrict__ s1)
{
    __shared__ __align__(16) unsigned short As[128*64];
    __shared__ __align__(16) unsigned short Bs[128*64];
    const unsigned b = blockIdx.x;
    const unsigned g = b / 33u, p = b % 33u;
    if (p < 8u){
        int id = g*8 + p;                       // 0..255
        sumexp128<1024>(Xb, hWb, sH, 2002, id >> 3, (id & 7)*2, (id & 7)*2 + 2, As, Bs);
    } else if (p < 17u){
        int id = g*9 + (p - 8);                 // 0..287
        sumexp128<256>(h0b, e0b, s0, 8000, id/9, (id%9)*7, (id%9)*7 + 7, As, Bs);
    } else {
        int id = g*16 + (p - 17);               // 0..511
        sumexp_stream128(h1b, e1b, s1, id*4 + (threadIdx.x >> 6));
    }
}

// ---------------- combine: target logits + assemble log-probs ---------------
__global__ __launch_bounds__(256) void k_combine(
    const unsigned short* __restrict__ Xb,   const unsigned short* __restrict__ hWb,
    const unsigned short* __restrict__ h0b,  const unsigned short* __restrict__ e0b,
    const unsigned short* __restrict__ h1b,  const unsigned short* __restrict__ e1b,
    const float* __restrict__ sH, const float* __restrict__ s0,
    const float* __restrict__ s1,
    const int* __restrict__ targets, float* __restrict__ out)
{
    int w = threadIdx.x >> 6, lane = threadIdx.x & 63;
    int row = blockIdx.x*4 + w;
    int t = targets[row];
    int hidx = t < 2000 ? t : (t < 10000 ? 2000 : 2001);
    int rel0 = min(max(t - 2000, 0), 7999);
    int rel1 = min(max(t - 10000, 0), 40256);

    float dh = 0.f;
    {
        const uint4* xa = (const uint4*)(Xb  + row*1024  + lane*16);
        const uint4* wb = (const uint4*)(hWb + hidx*1024 + lane*16);
        #pragma unroll
        for (int p = 0; p < 2; ++p){
            uint4 xv = xa[p], wv = wb[p];
            dh += dotu(xv.x, wv.x) + dotu(xv.y, wv.y)
                + dotu(xv.z, wv.z) + dotu(xv.w, wv.w);
        }
    }
    float d0;
    {
        uint2 xv = *(const uint2*)(h0b + row*256  + lane*4);
        uint2 wv = *(const uint2*)(e0b + rel0*256 + lane*4);
        d0 = dotu(xv.x, wv.x) + dotu(xv.y, wv.y);
    }
    float d1 = b2f(h1b[row*64 + lane]) * b2f(e1b[rel1*64 + lane]);

    #pragma unroll
    for (int m = 1; m < 64; m <<= 1){
        dh += __shfl_xor(dh, m, 64);
        d0 += __shfl_xor(d0, m, 64);
        d1 += __shfl_xor(d1, m, 64);
    }
    if (lane == 0){
        float lp = dh - log2f(sH[row]);
        if (t >= 2000 && t < 10000) lp += d0 - log2f(s0[row]);
        if (t >= 10000)             lp += d1 - log2f(s1[row]);
        out[row] = LN2 * lp;
    }
}

__global__ void k_loss(const float* __restrict__ out, float* __restrict__ loss){
    __shared__ float red[1024];
    float s = 0.f;
    for (int i = threadIdx.x; i < 4096; i += 1024) s += out[i];
    red[threadIdx.x] = s;
    __syncthreads();
    for (int ofs = 512; ofs > 0; ofs >>= 1){
        if (threadIdx.x < ofs) red[threadIdx.x] += red[threadIdx.x + ofs];
        __syncthreads();
    }
    if (threadIdx.x == 0) loss[0] = -red[0] / 4096.f;
}

// ---------------- host launch ----------------
extern "C" void kernel_launch(void* const* d_in, const int* in_sizes, int n_in,
                              void* d_out, int out_size, void* d_ws, size_t ws_size,
                              hipStream_t stream) {
    const float* X      = (const float*)d_in[0];
    const int*   tgt    = (const int*)  d_in[1];
    const float* headW  = (const float*)d_in[2];
    const float* emb0   = (const float*)d_in[3];
    const float* lin0   = (const float*)d_in[4];
    const float* emb1   = (const float*)d_in[5];
    const float* lin1   = (const float*)d_in[6];
    float* out = (float*)d_out;

    char* ws = (char*)d_ws;
    unsigned short* Xb  = (unsigned short*)(ws + 0);
    unsigned short* hWb = (unsigned short*)(ws + 8388608);
    unsigned short* e0b = (unsigned short*)(ws + 12488704);
    unsigned short* e1b = (unsigned short*)(ws + 16584704);
    unsigned short* l0T = (unsigned short*)(ws + 21737600);   // [256][1024]
    unsigned short* l1T = (unsigned short*)(ws + 22261888);   // [64][1024] (contiguous after l0T)
    unsigned short* h0b = (unsigned short*)(ws + 22392960);
    unsigned short* h1b = (unsigned short*)(ws + 24490112);
    float* sums         = (float*)(ws + 25014400);
    float* sH = sums, *s0 = sums + 4096, *s1 = sums + 8192;

    k_prep<<<2048, 256, 0, stream>>>(X, headW, emb0, emb1, lin0, lin1,
                                     Xb, hWb, e0b, e1b, l0T, l1T, sums);
    k_hgemm<<<96, 256, 0, stream>>>(Xb, l0T, h0b, h1b);
    k_sumexp<<<1056, 256, 0, stream>>>(Xb, hWb, h0b, e0b, h1b, e1b, sH, s0, s1);
    k_combine<<<1024, 256, 0, stream>>>(Xb, hWb, h0b, e0b, h1b, e1b,
                                        sH, s0, s1, tgt, out);
    k_loss<<<1, 1024, 0, stream>>>(out, out + 4096);
}

// Round 5
// 235.350 us; speedup vs baseline: 1.1719x; 1.1719x over previous
//
#include <hip/hip_runtime.h>

// AdaptiveSoftmax on MI355X — round 5.
// R4 post-mortem: m97-style 128-tile restructure REGRESSED (164us vs R3's
// 124us): parallelism dropped (1056 blocks, 148 VGPR) -> L2 temporal sharing
// collapsed, FETCH 41->287MB, occupancy 9%. This workload is thin+wide:
// concurrency beats per-block efficiency.
// R5: R3 skeleton (64x64 dbuf tiles, 2048 blocks, period-4 interleave,
// 4096-wave tail1 streaming) + global_load_lds(16B) staging replacing the
// VGPR round-trip (R3's VALU 37% -> target ~22%), XOR swizzle applied on the
// global address side so fragment reads keep R3's zero-conflict pattern.

typedef __attribute__((ext_vector_type(8))) short short8;
typedef __attribute__((ext_vector_type(4))) float f32x4;

#define LOG2E 1.4426950408889634f
#define LN2   0.6931471805599453f

__device__ __forceinline__ float b2f(unsigned short u){
    return __uint_as_float(((unsigned int)u) << 16);
}
__device__ __forceinline__ unsigned short f2b(float f){
    unsigned int x = __float_as_uint(f);
    x += 0x7fffu + ((x >> 16) & 1u);
    return (unsigned short)(x >> 16);
}
__device__ __forceinline__ float dotu(unsigned int xu, unsigned int wu){
    float a = __uint_as_float(xu << 16) * __uint_as_float(wu << 16);
    float b = __uint_as_float(xu & 0xffff0000u) * __uint_as_float(wu & 0xffff0000u);
    return a + b;
}
__device__ __forceinline__ float fexp2(float x){
#if __has_builtin(__builtin_amdgcn_exp2f)
    return __builtin_amdgcn_exp2f(x);
#else
    float r; asm("v_exp_f32 %0, %1" : "=v"(r) : "v"(x)); return r;
#endif
}
// async global->LDS: lane i's 16B land at lds_base + 16*i (lds_base wave-uniform)
__device__ __forceinline__ void gload16(const unsigned short* g, unsigned short* l){
    __builtin_amdgcn_global_load_lds(
        (const __attribute__((address_space(1))) unsigned int*)g,
        (__attribute__((address_space(3))) unsigned int*)l, 16, 0, 0);
}

// ---------------- prep: converts + LDS-tiled transposes + zero sums ---------
__global__ __launch_bounds__(256) void k_prep(
    const float* __restrict__ X, const float* __restrict__ headW,
    const float* __restrict__ emb0, const float* __restrict__ emb1,
    const float* __restrict__ lin0, const float* __restrict__ lin1,
    unsigned short* __restrict__ Xb, unsigned short* __restrict__ hWb,
    unsigned short* __restrict__ e0b, unsigned short* __restrict__ e1b,
    unsigned short* __restrict__ l0T, unsigned short* __restrict__ l1T,
    float* __restrict__ sums)
{
    __shared__ unsigned short tileT[64][65];
    const int b = blockIdx.x, t = threadIdx.x;
    if (b < 80){
        const float* src; unsigned short* dst; int C, tx, ty;
        if (b < 64){ src = lin0; dst = l0T; C = 256; tx = b & 3; ty = b >> 2; }
        else       { src = lin1; dst = l1T; C = 64;  tx = 0;     ty = b - 64; }
        #pragma unroll
        for (int e = 0; e < 16; ++e){
            int idx = t + e*256, r = idx >> 6, c = idx & 63;
            tileT[c][r] = f2b(src[(ty*64 + r)*C + tx*64 + c]);
        }
        __syncthreads();
        #pragma unroll
        for (int e = 0; e < 16; ++e){
            int idx = t + e*256, cc = idx >> 6, rr = idx & 63;
            dst[(tx*64 + cc)*1024 + ty*64 + rr] = tileT[cc][rr];
        }
        return;
    }
    const int NX = 1048576, NH = 512512, NE0 = 512000, NE1 = 644112;
    const int NV = NX + NH + NE0 + NE1;
    const int NS = 12288;
    const int total = NV + NS;
    int stride = (gridDim.x - 80) * blockDim.x;
    for (int i = (b - 80)*blockDim.x + t; i < total; i += stride){
        if (i < NV){
            const float* src; unsigned short* dst; int off; float sc;
            if (i < NX)            { src = X;     dst = Xb;  off = i;           sc = 1.0f;  }
            else if (i < NX+NH)    { src = headW; dst = hWb; off = i-NX;        sc = LOG2E; }
            else if (i < NX+NH+NE0){ src = emb0;  dst = e0b; off = i-NX-NH;     sc = LOG2E; }
            else                   { src = emb1;  dst = e1b; off = i-NX-NH-NE0; sc = LOG2E; }
            float4 v = ((const float4*)src)[off];
            ushort4 o;
            o.x = f2b(v.x*sc); o.y = f2b(v.y*sc);
            o.z = f2b(v.z*sc); o.w = f2b(v.w*sc);
            ((ushort4*)dst)[off] = o;
        } else {
            sums[i - NV] = 0.f;
        }
    }
}

// ---------------- h-GEMMs (K=1024, store bf16): h0 and h1 fused -------------
__global__ __launch_bounds__(256) void k_hgemm(
    const unsigned short* __restrict__ A,    // Xb [4096][1024]
    const unsigned short* __restrict__ B0, unsigned short* __restrict__ C0,
    const unsigned short* __restrict__ B1, unsigned short* __restrict__ C1)
{
    constexpr int K = 1024;
    __shared__ __align__(16) unsigned short As[64*64];
    __shared__ __align__(16) unsigned short Bs[64*64];

    const int yy = blockIdx.y;
    const unsigned short* B = (yy < 4) ? B0 : B1;
    unsigned short* C = (yy < 4) ? C0 : C1;
    const int M  = (yy < 4) ? 256 : 64;
    const int cb = (yy < 4) ? yy : 0;

    const int tid  = threadIdx.x;
    const int lane = tid & 63;
    const int w    = tid >> 6;
    const int waveR = w >> 1, waveC = w & 1;
    const int quad  = lane >> 4, l16 = lane & 15;
    const int row0  = blockIdx.x * 64;

    f32x4 acc[2][2];
    #pragma unroll
    for (int i = 0; i < 2; ++i)
    #pragma unroll
    for (int j = 0; j < 2; ++j)
        acc[i][j] = (f32x4){0.f, 0.f, 0.f, 0.f};

    for (int kc = 0; kc < K/64; ++kc){
        __syncthreads();
        #pragma unroll
        for (int it = 0; it < 2; ++it){
            int idx = tid + it*256;
            int r = idx >> 3, g = idx & 7;
            *((uint4*)&As[r*64 + ((g ^ (r & 7)) << 3)]) =
                *(const uint4*)(A + (row0 + r)*K + kc*64 + g*8);
            *((uint4*)&Bs[r*64 + ((g ^ (r & 7)) << 3)]) =
                *(const uint4*)(B + (cb*64 + r)*K + kc*64 + g*8);
        }
        __syncthreads();
        #pragma unroll
        for (int ks = 0; ks < 2; ++ks){
            short8 a[2], b[2];
            #pragma unroll
            for (int i = 0; i < 2; ++i){
                int r = waveR*32 + i*16 + l16;
                int g = ks*4 + quad;
                a[i] = *(const short8*)&As[r*64 + ((g ^ (r & 7)) << 3)];
            }
            #pragma unroll
            for (int j = 0; j < 2; ++j){
                int r = waveC*32 + j*16 + l16;
                int g = ks*4 + quad;
                b[j] = *(const short8*)&Bs[r*64 + ((g ^ (r & 7)) << 3)];
            }
            #pragma unroll
            for (int i = 0; i < 2; ++i)
            #pragma unroll
            for (int j = 0; j < 2; ++j)
                acc[i][j] = __builtin_amdgcn_mfma_f32_16x16x32_bf16(
                    a[i], b[j], acc[i][j], 0, 0, 0);
        }
    }
    #pragma unroll
    for (int i = 0; i < 2; ++i)
    #pragma unroll
    for (int j = 0; j < 2; ++j)
    #pragma unroll
    for (int r = 0; r < 4; ++r){
        int row = row0 + waveR*32 + i*16 + quad*4 + r;
        int col = cb*64 + waveC*32 + j*16 + l16;
        C[row*M + col] = f2b(acc[i][j][r]);
    }
}

// ------------- LDS GEMM+sumexp: 64x64 dbuf, global_load_lds staging ---------
// LDS tile layout: row r (0..63), 8 slots of 8 elems; slot s holds k-chunk
// s^(r&7). Staged by 4 waves x 2 issues of gload16 (8 rows x 128B each);
// lane fetches the permuted chunk so the lane-contiguous LDS write realizes
// the swizzle. One __syncthreads per k-step (drains vmcnt+lgkm).
template<int K>
__device__ __forceinline__ void sumexp_lds(
    const unsigned short* __restrict__ A,   // [4096][K]
    const unsigned short* __restrict__ B,   // [M][K] (pre-scaled by log2e)
    float* __restrict__ s_out, int M,
    int rowb, int cb0, int cb1,
    unsigned short* __restrict__ As,        // [2][64*64]
    unsigned short* __restrict__ Bs)
{
    constexpr int KCH = K / 64;
    constexpr int LK  = (KCH == 16) ? 4 : 2;
    static_assert(KCH == 16 || KCH == 4, "");
    const int tid  = threadIdx.x;
    const int lane = tid & 63, w = tid >> 6;
    const int waveR = w >> 1, waveC = w & 1;
    const int quad  = lane >> 4, l16 = lane & 15;
    const int row0  = rowb * 64;
    const int nit   = (cb1 - cb0) << LK;

    float s_loc[8];
    #pragma unroll
    for (int i = 0; i < 8; ++i) s_loc[i] = 0.f;
    f32x4 acc[2][2];
    #pragma unroll
    for (int i = 0; i < 2; ++i)
    #pragma unroll
    for (int j = 0; j < 2; ++j) acc[i][j] = (f32x4){0.f,0.f,0.f,0.f};

    // staging geometry: wave w covers rows w*16..w*16+15 in two 8-row issues
    const int sr = w*16 + (lane >> 3);              // issue c adds 8 ((sr+8)&7==sr&7)
    const int gk = ((lane & 7) ^ (sr & 7)) << 3;    // permuted k-chunk for this lane

    // fragment LDS read offsets (R3 pattern, measured zero-conflict)
    int aoff[2][2], boff[2][2];
    #pragma unroll
    for (int x = 0; x < 2; ++x)
    #pragma unroll
    for (int ks = 0; ks < 2; ++ks){
        int ra = waveR*32 + x*16 + l16;
        int rb = waveC*32 + x*16 + l16;
        int g  = ks*4 + quad;
        aoff[x][ks] = ra*64 + ((g ^ (ra & 7)) << 3);
        boff[x][ks] = rb*64 + ((g ^ (rb & 7)) << 3);
    }

    auto stage = [&](int it){
        int cb = cb0 + (it >> LK);
        int kc = it & (KCH - 1);
        unsigned short* Ad = As + (it & 1)*4096 + w*1024;   // rows w*16.. base
        unsigned short* Bd = Bs + (it & 1)*4096 + w*1024;
        const unsigned short* ga = A + (size_t)(row0 + sr)*K + kc*64 + gk;
        gload16(ga,        Ad);
        gload16(ga + 8*K,  Ad + 512);
        int br0 = cb*64 + sr;     if (br0 > M-1) br0 = M-1;
        int br1 = cb*64 + sr + 8; if (br1 > M-1) br1 = M-1;
        gload16(B + (size_t)br0*K + kc*64 + gk, Bd);
        gload16(B + (size_t)br1*K + kc*64 + gk, Bd + 512);
    };

    stage(0);
    __syncthreads();   // drains vmcnt: buf0 ready

    for (int it = 0; it < nit; ++it){
        if (it + 1 < nit) stage(it + 1);          // async into other buffer
        const unsigned short* Ac = As + (it & 1)*4096;
        const unsigned short* Bc = Bs + (it & 1)*4096;
        #pragma unroll
        for (int ks = 0; ks < 2; ++ks){
            short8 a0 = *(const short8*)(Ac + aoff[0][ks]);
            short8 a1 = *(const short8*)(Ac + aoff[1][ks]);
            short8 b0 = *(const short8*)(Bc + boff[0][ks]);
            short8 b1 = *(const short8*)(Bc + boff[1][ks]);
            acc[0][0] = __builtin_amdgcn_mfma_f32_16x16x32_bf16(a0, b0, acc[0][0], 0,0,0);
            acc[0][1] = __builtin_amdgcn_mfma_f32_16x16x32_bf16(a0, b1, acc[0][1], 0,0,0);
            acc[1][0] = __builtin_amdgcn_mfma_f32_16x16x32_bf16(a1, b0, acc[1][0], 0,0,0);
            acc[1][1] = __builtin_amdgcn_mfma_f32_16x16x32_bf16(a1, b1, acc[1][1], 0,0,0);
        }
        if ((it & (KCH - 1)) == (KCH - 1)){
            int cb = cb0 + (it >> LK);
            if ((cb + 1)*64 <= M){
                #pragma unroll
                for (int i = 0; i < 2; ++i)
                #pragma unroll
                for (int j = 0; j < 2; ++j)
                #pragma unroll
                for (int r = 0; r < 4; ++r)
                    s_loc[i*4 + r] += fexp2(acc[i][j][r]);
            } else {
                #pragma unroll
                for (int j = 0; j < 2; ++j){
                    int col = cb*64 + waveC*32 + j*16 + l16;
                    if (col < M){
                        #pragma unroll
                        for (int i = 0; i < 2; ++i)
                        #pragma unroll
                        for (int r = 0; r < 4; ++r)
                            s_loc[i*4 + r] += fexp2(acc[i][j][r]);
                    }
                }
            }
            #pragma unroll
            for (int i = 0; i < 2; ++i)
            #pragma unroll
            for (int j = 0; j < 2; ++j) acc[i][j] = (f32x4){0.f,0.f,0.f,0.f};
        }
        __syncthreads();   // drains stage(it+1) vmcnt + this iter's lgkm
    }

    #pragma unroll
    for (int k = 0; k < 8; ++k){
        #pragma unroll
        for (int m = 1; m < 16; m <<= 1)
            s_loc[k] += __shfl_xor(s_loc[k], m, 64);
    }
    if (l16 < 8){
        int i = l16 >> 2, r = l16 & 3;
        int row = row0 + waveR*32 + i*16 + quad*4 + r;
        atomicAdd(&s_out[row], s_loc[l16]);
    }
}

// ------------- tail1 (K=64): barrier-free streaming, 64 rows/wave -----------
__device__ __forceinline__ void sumexp_stream64(
    const unsigned short* __restrict__ A,   // h1b [4096][64]
    const unsigned short* __restrict__ B,   // e1b [40257][64] (scaled)
    float* __restrict__ s_out, int wid)     // wid in [0, 4096)
{
    const int M = 40257;
    const int lane = threadIdx.x & 63;
    const int quad = lane >> 4, l16 = lane & 15;
    const int rowg  = wid >> 6;
    const int split = wid & 63;
    const int g0 = split*39 + min(split, 21);
    const int g1 = g0 + 39 + (split < 21 ? 1 : 0);
    const int row0 = rowg * 64;

    short8 a[4][2];
    #pragma unroll
    for (int i = 0; i < 4; ++i)
    #pragma unroll
    for (int ks = 0; ks < 2; ++ks)
        a[i][ks] = *(const short8*)(A + (row0 + i*16 + l16)*64 + ks*32 + quad*8);

    f32x4 sums[4];
    #pragma unroll
    for (int i = 0; i < 4; ++i) sums[i] = (f32x4){0.f,0.f,0.f,0.f};

    short8 p0a, p1a, p0b, p1b;
    auto loadB = [&](int g, short8& d0, short8& d1){
        int n = g*16 + l16; if (n > M-1) n = M-1;
        const unsigned short* p = B + n*64 + quad*8;
        d0 = *(const short8*)p;
        d1 = *(const short8*)(p + 32);
    };
    auto body = [&](int g, short8 b0, short8 b1){
        f32x4 acc[4];
        #pragma unroll
        for (int i = 0; i < 4; ++i) acc[i] = (f32x4){0.f,0.f,0.f,0.f};
        #pragma unroll
        for (int i = 0; i < 4; ++i)
            acc[i] = __builtin_amdgcn_mfma_f32_16x16x32_bf16(a[i][0], b0, acc[i], 0,0,0);
        #pragma unroll
        for (int i = 0; i < 4; ++i)
            acc[i] = __builtin_amdgcn_mfma_f32_16x16x32_bf16(a[i][1], b1, acc[i], 0,0,0);
        if (g*16 + l16 < M){
            #pragma unroll
            for (int i = 0; i < 4; ++i){
                sums[i][0] += fexp2(acc[i][0]);
                sums[i][1] += fexp2(acc[i][1]);
                sums[i][2] += fexp2(acc[i][2]);
                sums[i][3] += fexp2(acc[i][3]);
            }
        }
    };

    loadB(g0, p0a, p1a);
    loadB(g0 + 1, p0b, p1b);
    for (int g = g0; g < g1; g += 2){
        body(g, p0a, p1a);
        if (g + 2 < g1) loadB(g + 2, p0a, p1a);
        if (g + 1 < g1){
            body(g + 1, p0b, p1b);
            if (g + 3 < g1) loadB(g + 3, p0b, p1b);
        }
    }

    #pragma unroll
    for (int i = 0; i < 4; ++i){
        #pragma unroll
        for (int r = 0; r < 4; ++r){
            float v = sums[i][r];
            v += __shfl_xor(v, 1, 64);
            v += __shfl_xor(v, 2, 64);
            v += __shfl_xor(v, 4, 64);
            v += __shfl_xor(v, 8, 64);
            if (l16 == 0)
                atomicAdd(&s_out[row0 + i*16 + quad*4 + r], v);
        }
    }
}

// ------------- fused sumexp dispatch (period-4 interleave, 2048 blocks) -----
__global__ __launch_bounds__(256) void k_sumexp(
    const unsigned short* __restrict__ Xb,  const unsigned short* __restrict__ hWb,
    const unsigned short* __restrict__ h0b, const unsigned short* __restrict__ e0b,
    const unsigned short* __restrict__ h1b, const unsigned short* __restrict__ e1b,
    float* __restrict__ sH, float* __restrict__ s0, float* __restrict__ s1)
{
    __shared__ __align__(16) unsigned short As[2*4096];
    __shared__ __align__(16) unsigned short Bs[2*4096];
    const int b = blockIdx.x;          // 2048 blocks: H,T1,T0,T1 repeating
    const int m4 = b & 3;
    if (m4 == 0){
        int id = b >> 2, rowb = id >> 3, split = id & 7;
        sumexp_lds<1024>(Xb, hWb, sH, 2002, rowb, split*4, split*4 + 4, As, Bs);
    } else if (m4 == 2){
        int id = b >> 2, rowb = id >> 3, split = id & 7;
        int cb0 = split*15 + min(split, 5);
        int cb1 = cb0 + 15 + (split < 5 ? 1 : 0);
        sumexp_lds<256>(h0b, e0b, s0, 8000, rowb, cb0, cb1, As, Bs);
    } else {
        int wid = (b >> 1)*4 + (threadIdx.x >> 6);
        sumexp_stream64(h1b, e1b, s1, wid);
    }
}

// ---------------- combine: target logits + assemble log-probs ---------------
__global__ __launch_bounds__(256) void k_combine(
    const unsigned short* __restrict__ Xb,   const unsigned short* __restrict__ hWb,
    const unsigned short* __restrict__ h0b,  const unsigned short* __restrict__ e0b,
    const unsigned short* __restrict__ h1b,  const unsigned short* __restrict__ e1b,
    const float* __restrict__ sH, const float* __restrict__ s0,
    const float* __restrict__ s1,
    const int* __restrict__ targets, float* __restrict__ out)
{
    int w = threadIdx.x >> 6, lane = threadIdx.x & 63;
    int row = blockIdx.x*4 + w;
    int t = targets[row];
    int hidx = t < 2000 ? t : (t < 10000 ? 2000 : 2001);
    int rel0 = min(max(t - 2000, 0), 7999);
    int rel1 = min(max(t - 10000, 0), 40256);

    float dh = 0.f;
    {
        const uint4* xa = (const uint4*)(Xb  + row*1024  + lane*16);
        const uint4* wb = (const uint4*)(hWb + hidx*1024 + lane*16);
        #pragma unroll
        for (int p = 0; p < 2; ++p){
            uint4 xv = xa[p], wv = wb[p];
            dh += dotu(xv.x, wv.x) + dotu(xv.y, wv.y)
                + dotu(xv.z, wv.z) + dotu(xv.w, wv.w);
        }
    }
    float d0;
    {
        uint2 xv = *(const uint2*)(h0b + row*256  + lane*4);
        uint2 wv = *(const uint2*)(e0b + rel0*256 + lane*4);
        d0 = dotu(xv.x, wv.x) + dotu(xv.y, wv.y);
    }
    float d1 = b2f(h1b[row*64 + lane]) * b2f(e1b[rel1*64 + lane]);

    #pragma unroll
    for (int m = 1; m < 64; m <<= 1){
        dh += __shfl_xor(dh, m, 64);
        d0 += __shfl_xor(d0, m, 64);
        d1 += __shfl_xor(d1, m, 64);
    }
    if (lane == 0){
        float lp = dh - log2f(sH[row]);
        if (t >= 2000 && t < 10000) lp += d0 - log2f(s0[row]);
        if (t >= 10000)             lp += d1 - log2f(s1[row]);
        out[row] = LN2 * lp;
    }
}

__global__ void k_loss(const float* __restrict__ out, float* __restrict__ loss){
    __shared__ float red[1024];
    float s = 0.f;
    for (int i = threadIdx.x; i < 4096; i += 1024) s += out[i];
    red[threadIdx.x] = s;
    __syncthreads();
    for (int ofs = 512; ofs > 0; ofs >>= 1){
        if (threadIdx.x < ofs) red[threadIdx.x] += red[threadIdx.x + ofs];
        __syncthreads();
    }
    if (threadIdx.x == 0) loss[0] = -red[0] / 4096.f;
}

// ---------------- host launch ----------------
extern "C" void kernel_launch(void* const* d_in, const int* in_sizes, int n_in,
                              void* d_out, int out_size, void* d_ws, size_t ws_size,
                              hipStream_t stream) {
    const float* X      = (const float*)d_in[0];
    const int*   tgt    = (const int*)  d_in[1];
    const float* headW  = (const float*)d_in[2];
    const float* emb0   = (const float*)d_in[3];
    const float* lin0   = (const float*)d_in[4];
    const float* emb1   = (const float*)d_in[5];
    const float* lin1   = (const float*)d_in[6];
    float* out = (float*)d_out;

    char* ws = (char*)d_ws;
    unsigned short* Xb  = (unsigned short*)(ws + 0);
    unsigned short* hWb = (unsigned short*)(ws + 8388608);
    unsigned short* e0b = (unsigned short*)(ws + 12488704);
    unsigned short* e1b = (unsigned short*)(ws + 16584704);
    unsigned short* l0T = (unsigned short*)(ws + 21737600);
    unsigned short* l1T = (unsigned short*)(ws + 22261888);
    unsigned short* h0b = (unsigned short*)(ws + 22392960);
    unsigned short* h1b = (unsigned short*)(ws + 24490112);
    float* sums         = (float*)(ws + 25014400);
    float* sH = sums, *s0 = sums + 4096, *s1 = sums + 8192;

    k_prep<<<2048, 256, 0, stream>>>(X, headW, emb0, emb1, lin0, lin1,
                                     Xb, hWb, e0b, e1b, l0T, l1T, sums);
    k_hgemm<<<dim3(64, 5), 256, 0, stream>>>(Xb, l0T, h0b, l1T, h1b);
    k_sumexp<<<2048, 256, 0, stream>>>(Xb, hWb, h0b, e0b, h1b, e1b, sH, s0, s1);
    k_combine<<<1024, 256, 0, stream>>>(Xb, hWb, h0b, e0b, h1b, e1b,
                                        sH, s0, s1, tgt, out);
    k_loss<<<1, 1024, 0, stream>>>(out, out + 4096);
}